// Round 1
// baseline (708.570 us; speedup 1.0000x reference)
//
#include <hip/hip_runtime.h>
#include <math.h>

#define CH 64
#define SLOPE 0.2f

// ---------------- CSR build ----------------

__global__ __launch_bounds__(256) void k_count(const int* __restrict__ ei,
                                               int* __restrict__ deg, int E) {
    int e = blockIdx.x * 256 + threadIdx.x;
    if (e < E) atomicAdd(&deg[ei[E + e]], 1);
}

// exclusive scan, stage 1: per-1024-chunk scan + chunk totals
__global__ __launch_bounds__(256) void k_scan1(const int* __restrict__ deg,
                                               int* __restrict__ rp,
                                               int* __restrict__ blk, int n) {
    __shared__ int sd[256];
    int t = threadIdx.x;
    int base = blockIdx.x * 1024 + t * 4;
    int v0 = 0, v1 = 0, v2 = 0, v3 = 0;
    if (base + 0 < n) v0 = deg[base + 0];
    if (base + 1 < n) v1 = deg[base + 1];
    if (base + 2 < n) v2 = deg[base + 2];
    if (base + 3 < n) v3 = deg[base + 3];
    int s = v0 + v1 + v2 + v3;
    sd[t] = s;
    __syncthreads();
    for (int off = 1; off < 256; off <<= 1) {
        int x = (t >= off) ? sd[t - off] : 0;
        __syncthreads();
        sd[t] += x;
        __syncthreads();
    }
    int ex = sd[t] - s;  // exclusive prefix of this thread within chunk
    if (t == 255) blk[blockIdx.x] = sd[255];
    if (base + 0 < n) rp[base + 0] = ex; ex += v0;
    if (base + 1 < n) rp[base + 1] = ex; ex += v1;
    if (base + 2 < n) rp[base + 2] = ex; ex += v2;
    if (base + 3 < n) rp[base + 3] = ex;
}

// stage 2: exclusive scan of chunk totals (nblk <= 256, runs in one block)
__global__ __launch_bounds__(256) void k_scan2(int* __restrict__ blk, int nblk) {
    __shared__ int sd[256];
    int t = threadIdx.x;
    int v = (t < nblk) ? blk[t] : 0;
    sd[t] = v;
    __syncthreads();
    for (int off = 1; off < 256; off <<= 1) {
        int x = (t >= off) ? sd[t - off] : 0;
        __syncthreads();
        sd[t] += x;
        __syncthreads();
    }
    if (t < nblk) blk[t] = sd[t] - v;
}

// stage 3: add chunk offsets; also init scatter cursors
__global__ __launch_bounds__(256) void k_scan3(int* __restrict__ rp,
                                               const int* __restrict__ blk,
                                               int* __restrict__ cur, int n) {
    int t = threadIdx.x;
    int base = blockIdx.x * 1024 + t * 4;
    int off = blk[blockIdx.x];
    #pragma unroll
    for (int i = 0; i < 4; i++) {
        int idx = base + i;
        if (idx < n) {
            int v = rp[idx] + off;
            rp[idx] = v;
            cur[idx] = v;
        }
    }
}

__global__ __launch_bounds__(256) void k_scatter(const int* __restrict__ ei,
                                                 int* __restrict__ cur,
                                                 int* __restrict__ col, int E) {
    int e = blockIdx.x * 256 + threadIdx.x;
    if (e < E) {
        int s = ei[e];
        int d = ei[E + e];
        int pos = atomicAdd(&cur[d], 1);
        col[pos] = s;
    }
}

// ---------------- GEMM: xl = in @ Wl, xr = in @ Wr ----------------
// One row per thread; both 64x64 weight matrices in LDS, read as broadcast float4.

__global__ __launch_bounds__(256) void k_gemm(const float* __restrict__ in,
                                              const float* __restrict__ Wl,
                                              const float* __restrict__ Wr,
                                              float* __restrict__ xl,
                                              float* __restrict__ xr, int n) {
    __shared__ float4 sW[64 * 32];  // [k][jg]: jg 0..15 -> Wl cols 4jg.., 16..31 -> Wr
    int t = threadIdx.x;
    for (int i = t; i < 2048; i += 256) {
        int k = i >> 5, jg = i & 31;
        const float* src = (jg < 16) ? (Wl + k * 64 + jg * 4)
                                     : (Wr + k * 64 + (jg - 16) * 4);
        sW[i] = *(const float4*)src;
    }
    __syncthreads();
    int r = blockIdx.x * 256 + t;
    if (r >= n) return;

    float xs[64];
    const float4* xp = (const float4*)(in + (size_t)r * 64);
    #pragma unroll
    for (int i = 0; i < 16; i++) {
        float4 v = xp[i];
        xs[4 * i + 0] = v.x; xs[4 * i + 1] = v.y;
        xs[4 * i + 2] = v.z; xs[4 * i + 3] = v.w;
    }
    for (int jg = 0; jg < 32; jg++) {
        float4 acc = {0.f, 0.f, 0.f, 0.f};
        #pragma unroll
        for (int k = 0; k < 64; k++) {
            float xk = xs[k];
            float4 w = sW[k * 32 + jg];
            acc.x += xk * w.x; acc.y += xk * w.y;
            acc.z += xk * w.z; acc.w += xk * w.w;
        }
        float* dst = (jg < 16) ? (xl + (size_t)r * 64 + jg * 4)
                               : (xr + (size_t)r * 64 + (jg - 16) * 4);
        *(float4*)dst = acc;
    }
}

// ---------------- node kernel: online-softmax GATv2 aggregation ----------------
// One wave (64 lanes) per node. lane = h*16 + o.

__global__ __launch_bounds__(256) void k_node(const float* __restrict__ xl,
                                              const float* __restrict__ xr,
                                              const int* __restrict__ rp,
                                              const int* __restrict__ deg,
                                              const int* __restrict__ col,
                                              const float* __restrict__ A,
                                              const float* __restrict__ Bv,
                                              float* __restrict__ outp,
                                              int n, int relu) {
    int lane = threadIdx.x & 63;
    int node = blockIdx.x * 4 + (threadIdx.x >> 6);
    if (node >= n) return;

    float xr_d = xr[(size_t)node * 64 + lane];
    float a_l = A[lane];   // a is [H,O] row-major; lane==h*16+o
    float b_l = Bv[lane];

    int start = rp[node];
    int d = deg[node];

    float m = -INFINITY, den = 0.f, acc = 0.f;
    for (int i = 0; i < d; i++) {
        int s = col[start + i];
        float xl_s = xl[(size_t)s * 64 + lane];
        float tsum = xl_s + xr_d;
        tsum = (tsum > 0.f) ? tsum : SLOPE * tsum;
        float p = tsum * a_l;
        // reduce over the 16-lane head group
        p += __shfl_xor(p, 1);
        p += __shfl_xor(p, 2);
        p += __shfl_xor(p, 4);
        p += __shfl_xor(p, 8);
        // online softmax update
        float mnew = fmaxf(m, p);
        float scale = __expf(m - mnew);   // first iter: exp(-inf) = 0
        float w = __expf(p - mnew);
        den = den * scale + w;
        acc = acc * scale + w * xl_s;
        m = mnew;
    }
    float o = acc / (den + 1e-16f) + b_l;
    if (relu) o = fmaxf(o, 0.f);
    outp[(size_t)node * 64 + lane] = o;
}

// ---------------- launcher ----------------

extern "C" void kernel_launch(void* const* d_in, const int* in_sizes, int n_in,
                              void* d_out, int out_size, void* d_ws, size_t ws_size,
                              hipStream_t stream) {
    const float* x = (const float*)d_in[0];
    const int* ei = (const int*)d_in[1];
    int N = in_sizes[0] / 64;
    int E = in_sizes[1] / 2;

    const float* Wl[3] = {(const float*)d_in[2], (const float*)d_in[6], (const float*)d_in[10]};
    const float* Wr[3] = {(const float*)d_in[3], (const float*)d_in[7], (const float*)d_in[11]};
    const float* Av[3] = {(const float*)d_in[4], (const float*)d_in[8], (const float*)d_in[12]};
    const float* Bv[3] = {(const float*)d_in[5], (const float*)d_in[9], (const float*)d_in[13]};

    // workspace carve (256B aligned)
    char* w = (char*)d_ws;
    auto carve = [&](size_t bytes) {
        void* p = (void*)w;
        w += (bytes + 255) & ~(size_t)255;
        return p;
    };
    float* xl  = (float*)carve((size_t)N * 64 * 4);
    float* xr  = (float*)carve((size_t)N * 64 * 4);
    float* h   = (float*)carve((size_t)N * 64 * 4);
    int*   rp  = (int*)carve((size_t)N * 4);
    int*   deg = (int*)carve((size_t)N * 4);
    int*   cur = (int*)carve((size_t)N * 4);
    int*   col = (int*)carve((size_t)E * 4);
    int*   blk = (int*)carve(256 * 4);

    int nblk1024 = (N + 1023) / 1024;

    // CSR build
    hipMemsetAsync(deg, 0, (size_t)N * 4, stream);
    k_count<<<(E + 255) / 256, 256, 0, stream>>>(ei, deg, E);
    k_scan1<<<nblk1024, 256, 0, stream>>>(deg, rp, blk, N);
    k_scan2<<<1, 256, 0, stream>>>(blk, nblk1024);
    k_scan3<<<nblk1024, 256, 0, stream>>>(rp, blk, cur, N);
    k_scatter<<<(E + 255) / 256, 256, 0, stream>>>(ei, cur, col, E);

    int gemm_grid = (N + 255) / 256;
    int node_grid = (N + 3) / 4;

    const float* in_l = x;
    for (int l = 0; l < 3; l++) {
        float* out_l = (l == 2) ? (float*)d_out : h;
        int relu = (l < 2) ? 1 : 0;
        k_gemm<<<gemm_grid, 256, 0, stream>>>(in_l, Wl[l], Wr[l], xl, xr, N);
        k_node<<<node_grid, 256, 0, stream>>>(xl, xr, rp, deg, col, Av[l], Bv[l],
                                              out_l, N, relu);
        in_l = h;
    }
}